// Round 13
// baseline (283.866 us; speedup 1.0000x reference)
//
#include <hip/hip_runtime.h>
#include <hip/hip_bf16.h>
#include <stdint.h>

#define NUM_IN  2048   // K
#define NUM_OUT 8192   // N
#define BATCH   4096   // M
#define SD      5

#define BM 256
#define BN 128
#define BK 32
#define NT (NUM_IN / BK)      // 64 K-tiles
#define ATILEE (BM * BK)      // 8192 elem (16 KB) per A buffer
#define BTILEE (BN * BK)      // 4096 elem (8 KB)  per B buffer

typedef __bf16 bf16x8 __attribute__((ext_vector_type(8)));
typedef float  f32x4  __attribute__((ext_vector_type(4)));
typedef unsigned short ushort_t;
typedef ushort_t ushort8 __attribute__((ext_vector_type(8)));

static __device__ __forceinline__ ushort_t bf16_bits(float f) {
  __hip_bfloat16 h = __float2bfloat16(f);
  ushort_t u;
  __builtin_memcpy(&u, &h, 2);
  return u;
}

// ---------- inputs f32 -> bf16 (vectorized) ----------
__global__ __launch_bounds__(256) void cvt_kernel(const float* __restrict__ x,
                                                  ushort_t* __restrict__ y) {
  const int i = (blockIdx.x * 256 + threadIdx.x) * 8;
  float4 v0 = *reinterpret_cast<const float4*>(x + i);
  float4 v1 = *reinterpret_cast<const float4*>(x + i + 4);
  ushort8 o;
  o[0] = bf16_bits(v0.x); o[1] = bf16_bits(v0.y);
  o[2] = bf16_bits(v0.z); o[3] = bf16_bits(v0.w);
  o[4] = bf16_bits(v1.x); o[5] = bf16_bits(v1.y);
  o[6] = bf16_bits(v1.z); o[7] = bf16_bits(v1.w);
  *reinterpret_cast<ushort8*>(y + i) = o;
}

// ---------- W^T generation: in_pos/init_in staged in LDS ----------
__global__ __launch_bounds__(256) void genw_kernel(
    const float* __restrict__ in_pos, const float* __restrict__ out_pos,
    const float* __restrict__ init_in, const float* __restrict__ init_out,
    ushort_t* __restrict__ Wt) {
  __shared__ float s_ip[NUM_IN * SD];    // 40 KB
  __shared__ float s_iip[NUM_IN * SD];   // 40 KB
  const int tid = threadIdx.x;
#pragma unroll
  for (int i = 0; i < 10; ++i) {
    const int idx = i * 1024 + tid * 4;
    *reinterpret_cast<float4*>(&s_ip[idx]) =
        *reinterpret_cast<const float4*>(in_pos + idx);
    *reinterpret_cast<float4*>(&s_iip[idx]) =
        *reinterpret_cast<const float4*>(init_in + idx);
  }
  __syncthreads();

  const int n  = blockIdx.x * 16 + (tid >> 4);
  const int kg = tid & 15;
  float op[SD], iop[SD];
#pragma unroll
  for (int d = 0; d < SD; ++d) {
    op[d]  = out_pos[n * SD + d];
    iop[d] = init_out[n * SD + d];
  }
#pragma unroll 1
  for (int kb = 0; kb < 16; ++kb) {
    const int k0 = kb * 128 + kg * 8;
    float buf[40], ibuf[40];
#pragma unroll
    for (int j = 0; j < 10; ++j) {
      float4 v = *reinterpret_cast<const float4*>(&s_ip[k0 * SD + j * 4]);
      buf[4 * j + 0] = v.x; buf[4 * j + 1] = v.y;
      buf[4 * j + 2] = v.z; buf[4 * j + 3] = v.w;
      float4 u = *reinterpret_cast<const float4*>(&s_iip[k0 * SD + j * 4]);
      ibuf[4 * j + 0] = u.x; ibuf[4 * j + 1] = u.y;
      ibuf[4 * j + 2] = u.z; ibuf[4 * j + 3] = u.w;
    }
    ushort8 o;
#pragma unroll
    for (int i = 0; i < 8; ++i) {
      float d1 = 0.f, d0 = 0.f;
#pragma unroll
      for (int d = 0; d < SD; ++d) {
        float a = buf[i * SD + d] - op[d];
        float b = ibuf[i * SD + d] - iop[d];
        d1 += a * a;
        d0 += b * b;
      }
      o[i] = bf16_bits(sqrtf(d1) - sqrtf(d0));
    }
    *reinterpret_cast<ushort8*>(Wt + (size_t)n * NUM_IN + k0) = o;
  }
}

// ---------- GEMM: 256x128 tile, 4 waves, 48KB LDS -> 2 blocks/CU ----------
// The m114 mechanism: two INDEPENDENT co-resident blocks per CU; one block's
// LDS read burst / barrier / epilogue overlaps the other's MFMA clusters.
// Register math: 4 waves x ~232 unified regs x 2 blocks = 1856 <= 2048/CU.
// Within a block: r7's counted-lgkm lookahead KTILE, BK=32 dbuf,
// one barrier + one vmcnt(0) per K-tile.
// Layout/swizzle verified zero-conflict (r8-r12): row-paired 128B lines,
// line L=row>>1, logical chunk c=4*(row&1)+ck stored at c^(L&7).
__global__ __launch_bounds__(256, 1) void gemm_kernel(
    const ushort_t* __restrict__ A,    // [M][K] bf16
    const ushort_t* __restrict__ Bt,   // [N][K] bf16
    const float* __restrict__ bias,    // [N]
    float* __restrict__ C) {           // [M][N] f32
  __shared__ __align__(16) ushort_t sA[2 * ATILEE];   // 32 KiB
  __shared__ __align__(16) ushort_t sB[2 * BTILEE];   // 16 KiB

  const int tid  = threadIdx.x;
  const int w    = tid >> 6;         // 0..3
  const int l    = tid & 63;
  const int wm   = w >> 1;           // 0..1  (M half: 128 rows)
  const int wn   = w & 1;            // 0..1  (N half: 64 cols)
  const int lrow = l & 15;
  const int lkc  = l >> 4;           // 0..3

  // bijective XCD swizzle (1024 = 8*128)
  const int orig = blockIdx.x;
  const int lin  = (orig & 7) * 128 + (orig >> 3);
  const int bx   = lin >> 4;         // 0..63 N-block
  const int by   = lin & 15;         // 0..15 M-block
  const int m0   = by * BM;
  const int n0   = bx * BN;

  // ---- fragment lane offset (elements) ----
  const int phys  = ((4 * (lrow & 1) + lkc) ^ (lrow >> 1));
  const int laneo = (lrow >> 1) * 64 + phys * 8;
  const int AbW = wm * 4096;   // + mh*2048 + mi*512
  const int BbW = wn * 2048;   // + nh*1024 + nj*512

  // ---- staging geometry ----
  // A: 1024 chunks (d = tid + i*256, i=0..3); B: 512 chunks (i=0..1)
  // line = d>>3, physc = d&7, logical c = physc^(line&7),
  // src row = 2*line + (c>>2), k-off = (c&3)*8; LDS dest = d*8 (linear)
#define SRC_GEOM(d, rowv, kev)                                                 \
  {                                                                            \
    const int c_ = ((d) & 7) ^ (((d) >> 3) & 7);                               \
    rowv = 2 * ((d) >> 3) + (c_ >> 2);                                         \
    kev  = (c_ & 3) * 8;                                                       \
  }
  int rA0, kA0, rA1, kA1, rA2, kA2e, rA3, kA3;
  int rB0, kB0, rB1, kB1;
  SRC_GEOM(tid,        rA0, kA0)
  SRC_GEOM(tid + 256,  rA1, kA1)
  SRC_GEOM(tid + 512,  rA2, kA2e)
  SRC_GEOM(tid + 768,  rA3, kA3)
  rB0 = rA0; kB0 = kA0;
  rB1 = rA1; kB1 = kA1;
  const ushort_t* pA0 = A  + (size_t)(m0 + rA0) * NUM_IN + kA0;
  const ushort_t* pA1 = A  + (size_t)(m0 + rA1) * NUM_IN + kA1;
  const ushort_t* pA2 = A  + (size_t)(m0 + rA2) * NUM_IN + kA2e;
  const ushort_t* pA3 = A  + (size_t)(m0 + rA3) * NUM_IN + kA3;
  const ushort_t* pB0 = Bt + (size_t)(n0 + rB0) * NUM_IN + kB0;
  const ushort_t* pB1 = Bt + (size_t)(n0 + rB1) * NUM_IN + kB1;

#define GLDS(src, dst)                                                         \
  __builtin_amdgcn_global_load_lds(                                            \
      reinterpret_cast<const __attribute__((address_space(1))) uint32_t*>(     \
          (uintptr_t)(src)),                                                   \
      reinterpret_cast<__attribute__((address_space(3))) uint32_t*>(           \
          (uintptr_t)(dst)),                                                   \
      16, 0, 0)

// one K-tile stage = 6 gloads/thread (A:4, B:2)
#define STAGE(bs, kt)                                                          \
  {                                                                            \
    GLDS(pA0 + (kt), &sA[(bs) * ATILEE + tid * 8]);                            \
    GLDS(pA1 + (kt), &sA[(bs) * ATILEE + tid * 8 + 2048]);                     \
    GLDS(pA2 + (kt), &sA[(bs) * ATILEE + tid * 8 + 4096]);                     \
    GLDS(pA3 + (kt), &sA[(bs) * ATILEE + tid * 8 + 6144]);                     \
    GLDS(pB0 + (kt), &sB[(bs) * BTILEE + tid * 8]);                            \
    GLDS(pB1 + (kt), &sB[(bs) * BTILEE + tid * 8 + 2048]);                     \
  }

#define RD_A(arr, bs, mh)                                                      \
  {                                                                            \
    _Pragma("unroll")                                                          \
    for (int mi = 0; mi < 4; ++mi)                                             \
      arr[mi] = *reinterpret_cast<const bf16x8*>(                              \
          &sA[(bs) * ATILEE + AbW + (mh) * 2048 + mi * 512 + laneo]);          \
  }
#define RD_B(arr, bs, nh)                                                      \
  {                                                                            \
    _Pragma("unroll")                                                          \
    for (int nj = 0; nj < 2; ++nj)                                             \
      arr[nj] = *reinterpret_cast<const bf16x8*>(                              \
          &sB[(bs) * BTILEE + BbW + (nh) * 1024 + nj * 512 + laneo]);          \
  }

#define MFMA8(mh, nh, Aa, Bx)                                                  \
  {                                                                            \
    __builtin_amdgcn_s_setprio(1);                                             \
    _Pragma("unroll")                                                          \
    for (int mi = 0; mi < 4; ++mi)                                             \
      _Pragma("unroll")                                                        \
      for (int nj = 0; nj < 2; ++nj)                                           \
        acc[(mh) * 4 + mi][(nh) * 2 + nj] =                                    \
            __builtin_amdgcn_mfma_f32_16x16x32_bf16(                           \
                Aa[mi], Bx[nj], acc[(mh) * 4 + mi][(nh) * 2 + nj], 0, 0, 0);   \
    __builtin_amdgcn_s_setprio(0);                                             \
  }

#define LGKM(n)  asm volatile("s_waitcnt lgkmcnt(" #n ")" ::: "memory")
#define SCHED0   __builtin_amdgcn_sched_barrier(0)
#define BARRIER  __builtin_amdgcn_s_barrier()
#define VMCNT0   asm volatile("s_waitcnt vmcnt(0)" ::: "memory")

// r7 lookahead KTILE: counted-lgkm, reads buf CUR, stages buf NXT.
#define KTILE(CUR, NXT, ktn)                                                   \
  {                                                                            \
    STAGE(NXT, ktn)                                                            \
    RD_A(aE, CUR, 0) RD_B(b0, CUR, 0)                                          \
    RD_B(b1, CUR, 1)                                                           \
    LGKM(2); SCHED0;                                                           \
    MFMA8(0, 0, aE, b0)                                                        \
    RD_A(aO, CUR, 1)                                                           \
    LGKM(4); SCHED0;                                                           \
    MFMA8(0, 1, aE, b1)                                                        \
    LGKM(0); SCHED0;                                                           \
    MFMA8(1, 0, aO, b0)                                                        \
    MFMA8(1, 1, aO, b1)                                                        \
    VMCNT0;                                                                    \
    BARRIER;                                                                   \
  }

  f32x4 acc[8][4];
#pragma unroll
  for (int i = 0; i < 8; ++i)
#pragma unroll
    for (int j = 0; j < 4; ++j) acc[i][j] = f32x4{0.f, 0.f, 0.f, 0.f};

  bf16x8 aE[4], aO[4], b0[2], b1[2];

  // prologue: stage tile 0 into buf0
  STAGE(0, 0)
  VMCNT0;
  BARRIER;

#pragma unroll 1
  for (int tt = 0; tt < NT; tt += 2) {
    const int k1 = (tt + 1 < NT ? tt + 1 : NT - 1) * BK;
    const int k2 = (tt + 2 < NT ? tt + 2 : NT - 1) * BK;
    KTILE(0, 1, k1)
    KTILE(1, 0, k2)
  }

  // ---- epilogue: C = acc + bias ----
  const int er = l >> 4;          // 0..3
  const int ec = l & 15;
#pragma unroll
  for (int nh = 0; nh < 2; ++nh) {
#pragma unroll
    for (int nj = 0; nj < 2; ++nj) {
      const int col = n0 + wn * 64 + nh * 32 + nj * 16 + ec;
      const float bi = bias[col];
#pragma unroll
      for (int mh = 0; mh < 2; ++mh) {
#pragma unroll
        for (int mi = 0; mi < 4; ++mi) {
#pragma unroll
          for (int j = 0; j < 4; ++j) {
            const int row = m0 + wm * 128 + mh * 64 + mi * 16 + er * 4 + j;
            C[(size_t)row * NUM_OUT + col] =
                acc[mh * 4 + mi][nh * 2 + nj][j] + bi;
          }
        }
      }
    }
  }
#undef KTILE
#undef STAGE
#undef RD_A
#undef RD_B
#undef MFMA8
#undef GLDS
#undef SRC_GEOM
}

extern "C" void kernel_launch(void* const* d_in, const int* in_sizes, int n_in,
                              void* d_out, int out_size, void* d_ws, size_t ws_size,
                              hipStream_t stream) {
  const float* inputs   = (const float*)d_in[0];  // [4096,2048]
  const float* init_in  = (const float*)d_in[1];  // [2048,1,5]
  const float* init_out = (const float*)d_in[2];  // [1,8192,5]
  const float* in_pos   = (const float*)d_in[3];  // [2048,1,5]
  const float* out_pos  = (const float*)d_in[4];  // [1,8192,5]
  const float* biases   = (const float*)d_in[5];  // [8192]
  float* out = (float*)d_out;                     // [4096,8192]

  ushort_t* Abf = (ushort_t*)d_ws;
  ushort_t* Wt  = (ushort_t*)((char*)d_ws + (size_t)BATCH * NUM_IN * 2);

  cvt_kernel<<<(BATCH * NUM_IN) / (256 * 8), 256, 0, stream>>>(inputs, Abf);
  genw_kernel<<<NUM_OUT / 16, 256, 0, stream>>>(
      in_pos, out_pos, init_in, init_out, Wt);
  gemm_kernel<<<(BATCH / BM) * (NUM_OUT / BN), 256, 0, stream>>>(
      Abf, Wt, biases, out);
}

// Round 14
// 152.946 us; speedup vs baseline: 1.8560x; 1.8560x over previous
//
#include <hip/hip_runtime.h>
#include <hip/hip_bf16.h>
#include <stdint.h>

#define NUM_IN  2048   // K
#define NUM_OUT 8192   // N
#define BATCH   4096   // M
#define SD      5

#define BM 256
#define BN 256
#define BK 64
#define NT (NUM_IN / BK)      // 32 K-tiles
#define TILEE (BM * BK)       // 16384 elements per operand per K-tile

typedef __bf16 bf16x8 __attribute__((ext_vector_type(8)));
typedef float  f32x4  __attribute__((ext_vector_type(4)));
typedef unsigned short ushort_t;
typedef ushort_t ushort8 __attribute__((ext_vector_type(8)));

static __device__ __forceinline__ ushort_t bf16_bits(float f) {
  __hip_bfloat16 h = __float2bfloat16(f);
  ushort_t u;
  __builtin_memcpy(&u, &h, 2);
  return u;
}

// ---------- fused aux: blocks [0,512) genw, [512,1024) cvt ----------
// genw: 16 n per block, in_pos/init_in staged in LDS (80 KB).
// cvt: 16384 f32->bf16 per block, fully coalesced.
// Independent workloads run CONCURRENTLY across CUs (one launch).
__global__ __launch_bounds__(256) void aux_kernel(
    const float* __restrict__ inputs,   // [BATCH][NUM_IN] f32
    ushort_t* __restrict__ Abf,         // [BATCH][NUM_IN] bf16
    const float* __restrict__ in_pos, const float* __restrict__ out_pos,
    const float* __restrict__ init_in, const float* __restrict__ init_out,
    ushort_t* __restrict__ Wt) {        // [NUM_OUT][NUM_IN] bf16
  __shared__ float s_ip[NUM_IN * SD];    // 40 KB
  __shared__ float s_iip[NUM_IN * SD];   // 40 KB
  const int tid = threadIdx.x;

  if (blockIdx.x >= 512) {
    // ---- cvt path ----
    const size_t base = (size_t)(blockIdx.x - 512) * 16384;
#pragma unroll
    for (int c = 0; c < 8; ++c) {
      const size_t i = base + (size_t)c * 2048 + tid * 8;
      float4 v0 = *reinterpret_cast<const float4*>(inputs + i);
      float4 v1 = *reinterpret_cast<const float4*>(inputs + i + 4);
      ushort8 o;
      o[0] = bf16_bits(v0.x); o[1] = bf16_bits(v0.y);
      o[2] = bf16_bits(v0.z); o[3] = bf16_bits(v0.w);
      o[4] = bf16_bits(v1.x); o[5] = bf16_bits(v1.y);
      o[6] = bf16_bits(v1.z); o[7] = bf16_bits(v1.w);
      *reinterpret_cast<ushort8*>(Abf + i) = o;
    }
    return;
  }

  // ---- genw path ----
#pragma unroll
  for (int i = 0; i < 10; ++i) {
    const int idx = i * 1024 + tid * 4;
    *reinterpret_cast<float4*>(&s_ip[idx]) =
        *reinterpret_cast<const float4*>(in_pos + idx);
    *reinterpret_cast<float4*>(&s_iip[idx]) =
        *reinterpret_cast<const float4*>(init_in + idx);
  }
  __syncthreads();

  const int n  = blockIdx.x * 16 + (tid >> 4);
  const int kg = tid & 15;
  float op[SD], iop[SD];
#pragma unroll
  for (int d = 0; d < SD; ++d) {
    op[d]  = out_pos[n * SD + d];
    iop[d] = init_out[n * SD + d];
  }
#pragma unroll 1
  for (int kb = 0; kb < 16; ++kb) {
    const int k0 = kb * 128 + kg * 8;
    float buf[40], ibuf[40];
#pragma unroll
    for (int j = 0; j < 10; ++j) {
      float4 v = *reinterpret_cast<const float4*>(&s_ip[k0 * SD + j * 4]);
      buf[4 * j + 0] = v.x; buf[4 * j + 1] = v.y;
      buf[4 * j + 2] = v.z; buf[4 * j + 3] = v.w;
      float4 u = *reinterpret_cast<const float4*>(&s_iip[k0 * SD + j * 4]);
      ibuf[4 * j + 0] = u.x; ibuf[4 * j + 1] = u.y;
      ibuf[4 * j + 2] = u.z; ibuf[4 * j + 3] = u.w;
    }
    ushort8 o;
#pragma unroll
    for (int i = 0; i < 8; ++i) {
      float d1 = 0.f, d0 = 0.f;
#pragma unroll
      for (int d = 0; d < SD; ++d) {
        float a = buf[i * SD + d] - op[d];
        float b = ibuf[i * SD + d] - iop[d];
        d1 += a * a;
        d0 += b * b;
      }
      o[i] = bf16_bits(sqrtf(d1) - sqrtf(d0));
    }
    *reinterpret_cast<ushort8*>(Wt + (size_t)n * NUM_IN + k0) = o;
  }
}

// ---------- GEMM: round-7 kernel verbatim (best measured: 128.6us, 47.5%) ----
// de-lockstepped 256^2, 1 barrier per K-tile, dbuf BK=64, counted-lgkm
// read lookahead. 128B rows, chunk c stored at c^(row&7) (measured-zero).
__global__ __launch_bounds__(512, 1) void gemm_kernel(
    const ushort_t* __restrict__ A,    // [M][K] bf16
    const ushort_t* __restrict__ Bt,   // [N][K] bf16
    const float* __restrict__ bias,    // [N]
    float* __restrict__ C) {           // [M][N] f32
  __shared__ __align__(16) ushort_t sA[2 * TILEE];   // 64 KiB
  __shared__ __align__(16) ushort_t sB[2 * TILEE];   // 64 KiB

  const int tid  = threadIdx.x;
  const int w    = tid >> 6;         // 0..7
  const int l    = tid & 63;
  const int wm   = w >> 2;           // 0..1
  const int wn   = w & 3;            // 0..3
  const int lrow = l & 15;
  const int lkc  = l >> 4;           // 0..3

  // bijective XCD swizzle (512 = 8*64)
  const int orig = blockIdx.x;
  const int lin  = (orig & 7) * 64 + (orig >> 3);
  const int bx   = lin >> 4;         // 0..31 N-block
  const int by   = lin & 15;         // 0..15 M-block
  const int m0   = by * BM;
  const int n0   = bx * BN;

  // fragment read constants (elements)
  const int ck0 = (lkc ^ (lrow & 7)) * 8;         // k-half 0
  const int ck1 = ((4 + lkc) ^ (lrow & 7)) * 8;   // k-half 1
  const int Ab  = wm * 4096 + lrow * 64;
  const int Bb  = wn * 2048 + lrow * 64;

  // staging geometry (verified zero-conflict)
  const int d0 = tid, d1 = tid + 512;
  const int lr0 = d0 >> 3, lr1 = d1 >> 3;
  const int c0 = (d0 & 7) ^ (lr0 & 7);
  const int c1 = (d1 & 7) ^ (lr1 & 7);
  const ushort_t* pA0 = A  + (size_t)(m0 + (lr0 >> 6) * 128 + (lr0 & 63)) * NUM_IN + c0 * 8;
  const ushort_t* pA1 = A  + (size_t)(m0 + (lr1 >> 6) * 128 + (lr1 & 63)) * NUM_IN + c1 * 8;
  const ushort_t* pB0 = Bt + (size_t)(n0 + (lr0 >> 5) * 64 + (lr0 & 31)) * NUM_IN + c0 * 8;
  const ushort_t* pB1 = Bt + (size_t)(n0 + (lr1 >> 5) * 64 + (lr1 & 31)) * NUM_IN + c1 * 8;

#define GLDS(src, dst)                                                         \
  __builtin_amdgcn_global_load_lds(                                            \
      reinterpret_cast<const __attribute__((address_space(1))) uint32_t*>(     \
          (uintptr_t)(src)),                                                   \
      reinterpret_cast<__attribute__((address_space(3))) uint32_t*>(           \
          (uintptr_t)(dst)),                                                   \
      16, 0, 0)

#define STAGE_A(bs, mh, kt)                                                    \
  {                                                                            \
    GLDS(pA0 + (size_t)(mh) * 64 * NUM_IN + (kt),                              \
         &sA[(bs) * TILEE + (mh) * 8192 + tid * 8]);                           \
    GLDS(pA1 + (size_t)(mh) * 64 * NUM_IN + (kt),                              \
         &sA[(bs) * TILEE + (mh) * 8192 + tid * 8 + 4096]);                    \
  }
#define STAGE_B(bs, nh, kt)                                                    \
  {                                                                            \
    GLDS(pB0 + (size_t)(nh) * 32 * NUM_IN + (kt),                              \
         &sB[(bs) * TILEE + (nh) * 8192 + tid * 8]);                           \
    GLDS(pB1 + (size_t)(nh) * 32 * NUM_IN + (kt),                              \
         &sB[(bs) * TILEE + (nh) * 8192 + tid * 8 + 4096]);                    \
  }

// 4 ds_read_b128: one A-half, one k-half
#define RD_A(arr, bs, mh, ck)                                                  \
  {                                                                            \
    _Pragma("unroll")                                                          \
    for (int mi = 0; mi < 4; ++mi)                                             \
      arr[mi] = *reinterpret_cast<const bf16x8*>(                              \
          &sA[(bs) * TILEE + (mh) * 8192 + Ab + mi * 1024 + (ck)]);            \
  }
// 2 ds_read_b128: one B-half, one k-half
#define RD_B(arr, bs, nh, ck)                                                  \
  {                                                                            \
    _Pragma("unroll")                                                          \
    for (int nj = 0; nj < 2; ++nj)                                             \
      arr[nj] = *reinterpret_cast<const bf16x8*>(                              \
          &sB[(bs) * TILEE + (nh) * 8192 + Bb + nj * 1024 + (ck)]);            \
  }

// 8 MFMA: one C-quadrant x one k-half
#define MFMA8(mh, nh, Aa, Bb_)                                                 \
  {                                                                            \
    __builtin_amdgcn_s_setprio(1);                                             \
    _Pragma("unroll")                                                          \
    for (int mi = 0; mi < 4; ++mi)                                             \
      _Pragma("unroll")                                                        \
      for (int nj = 0; nj < 2; ++nj)                                           \
        acc[(mh) * 4 + mi][(nh) * 2 + nj] =                                    \
            __builtin_amdgcn_mfma_f32_16x16x32_bf16(                           \
                Aa[mi], Bb_[nj], acc[(mh) * 4 + mi][(nh) * 2 + nj], 0, 0, 0);  \
    __builtin_amdgcn_s_setprio(0);                                             \
  }

#define LGKM(n)  asm volatile("s_waitcnt lgkmcnt(" #n ")" ::: "memory")
#define SCHED0   __builtin_amdgcn_sched_barrier(0)
#define BARRIER  __builtin_amdgcn_s_barrier()
#define VMCNT0   asm volatile("s_waitcnt vmcnt(0)" ::: "memory")

#define KTILE(CUR, NXT, ktn)                                                   \
  {                                                                            \
    STAGE_A(NXT, 0, ktn)                                                       \
    RD_A(aE, CUR, 0, ck0) RD_B(b0, CUR, 0, ck0)                                \
    RD_B(b1, CUR, 1, ck0)                    /* lookahead R1 */                \
    LGKM(2); SCHED0;                                                           \
    MFMA8(0, 0, aE, b0)                                                        \
    STAGE_B(NXT, 0, ktn)                                                       \
    RD_A(aO, CUR, 1, ck0)                    /* lookahead R2 */                \
    LGKM(4); SCHED0;                                                           \
    MFMA8(0, 1, aE, b1)                                                        \
    STAGE_A(NXT, 1, ktn)                                                       \
    LGKM(0); SCHED0;                                                           \
    MFMA8(1, 0, aO, b0)                                                        \
    STAGE_B(NXT, 1, ktn)                                                       \
    RD_A(aE, CUR, 0, ck1) RD_B(b0, CUR, 0, ck1)  /* lookahead R4 */            \
    MFMA8(1, 1, aO, b1)                                                        \
    RD_B(b1, CUR, 1, ck1)                    /* lookahead R5 */                \
    LGKM(2); SCHED0;                                                           \
    MFMA8(0, 0, aE, b0)                                                        \
    RD_A(aO, CUR, 1, ck1)                    /* lookahead R6 */                \
    LGKM(4); SCHED0;                                                           \
    MFMA8(0, 1, aE, b1)                                                        \
    LGKM(0); SCHED0;                                                           \
    MFMA8(1, 0, aO, b0)                                                        \
    MFMA8(1, 1, aO, b1)                                                        \
    VMCNT0;                                                                    \
    BARRIER;                                                                   \
  }

  f32x4 acc[8][4];
#pragma unroll
  for (int i = 0; i < 8; ++i)
#pragma unroll
    for (int j = 0; j < 4; ++j) acc[i][j] = f32x4{0.f, 0.f, 0.f, 0.f};

  bf16x8 aE[4], aO[4], b0[2], b1[2];

  // prologue: stage tile 0 into buf0
  STAGE_A(0, 0, 0) STAGE_B(0, 0, 0) STAGE_A(0, 1, 0) STAGE_B(0, 1, 0)
  VMCNT0;
  BARRIER;

#pragma unroll 1
  for (int tt = 0; tt < NT; tt += 2) {
    const int k1 = (tt + 1) * BK;                          // always < NUM_IN
    const int k2 = (tt + 2 < NT ? tt + 2 : NT - 1) * BK;   // clamped tail
    KTILE(0, 1, k1)
    KTILE(1, 0, k2)
  }

  // ---- epilogue: C = acc + bias ----
  const int er = l >> 4;          // 0..3
  const int ec = l & 15;
#pragma unroll
  for (int nh = 0; nh < 2; ++nh) {
#pragma unroll
    for (int nj = 0; nj < 2; ++nj) {
      const int col = n0 + wn * 64 + nh * 32 + nj * 16 + ec;
      const float bi = bias[col];
#pragma unroll
      for (int mh = 0; mh < 2; ++mh) {
#pragma unroll
        for (int mi = 0; mi < 4; ++mi) {
#pragma unroll
          for (int j = 0; j < 4; ++j) {
            const int row = m0 + wm * 128 + mh * 64 + mi * 16 + er * 4 + j;
            C[(size_t)row * NUM_OUT + col] =
                acc[mh * 4 + mi][nh * 2 + nj][j] + bi;
          }
        }
      }
    }
  }
#undef KTILE
#undef STAGE_A
#undef STAGE_B
#undef RD_A
#undef RD_B
#undef MFMA8
#undef GLDS
}

extern "C" void kernel_launch(void* const* d_in, const int* in_sizes, int n_in,
                              void* d_out, int out_size, void* d_ws, size_t ws_size,
                              hipStream_t stream) {
  const float* inputs   = (const float*)d_in[0];  // [4096,2048]
  const float* init_in  = (const float*)d_in[1];  // [2048,1,5]
  const float* init_out = (const float*)d_in[2];  // [1,8192,5]
  const float* in_pos   = (const float*)d_in[3];  // [2048,1,5]
  const float* out_pos  = (const float*)d_in[4];  // [1,8192,5]
  const float* biases   = (const float*)d_in[5];  // [8192]
  float* out = (float*)d_out;                     // [4096,8192]

  ushort_t* Abf = (ushort_t*)d_ws;
  ushort_t* Wt  = (ushort_t*)((char*)d_ws + (size_t)BATCH * NUM_IN * 2);

  aux_kernel<<<1024, 256, 0, stream>>>(inputs, Abf,
                                       in_pos, out_pos, init_in, init_out, Wt);
  gemm_kernel<<<(BATCH / BM) * (NUM_OUT / BN), 512, 0, stream>>>(
      Abf, Wt, biases, out);
}